// Round 1
// baseline (1202.192 us; speedup 1.0000x reference)
//
#include <hip/hip_runtime.h>
#include <stdint.h>
#include <math.h>

// ---------------------------------------------------------------------------
// HebbianGroupMemory on MI355X (gfx950)
//   pair_embed [8,2048,1024] f32  -> flat [N=16384, D=1024]
//   patterns   [G=4096, D=1024] f32
//   usage      [G=4096] f32
// Outputs (concat f32): weights [16384,4096], patterns_new [4096,1024], usage_new [4096]
//
// Pipeline:
//   1. prep_scalars:  hscaled[g] = log(max(usage,EPS))/TEMP ; wsum[g]=0
//   2. norm_rows:     q_bf16 = l2norm(flat) as bf16 ; pat_bf16 = l2norm(patterns)
//   3. transpose:     fT = flat^T as bf16 [1024,16384]   (for GEMM2 B-operand)
//   4. gemm1 (MFMA bf16 16x16x32, 128x128 tile, BK=64):  s = Q·P^T/T - hscaled
//   5. softmax rows (32 rows/block, row in regs) + per-thread colsum -> atomicAdd wsum
//   6. usage_kernel:  usage_new ; invw = 1/(wsum+EPS)
//   7. transpose:     wT = weights^T as bf16 [4096,16384]
//   8. gemm2 (same tile structure): blended_pre = 0.97*pat + 0.03*acc*invw[g]
//   9. finalize: row-l2norm blended_pre (select original patterns if !valid)
// ---------------------------------------------------------------------------

#define DECAY 0.97f
#define OMD 0.03f                 // 1 - DECAY
#define INV_TEMP (1.0f / 0.7f)
#define EPS 1e-6f
#define NORM_EPS 1e-12f

constexpr int NROWS = 16384;      // 8*2048
constexpr int DK = 1024;
constexpr int GP = 4096;

typedef unsigned short u16;
typedef __bf16 bf16x8 __attribute__((ext_vector_type(8)));   // gfx950 MFMA A/B operand (V8y)
typedef float f32x4 __attribute__((ext_vector_type(4)));      // MFMA C/D

// round-to-nearest-even f32 -> bf16 (as raw u16)
__device__ inline u16 f2bf(float x) {
    union { float f; uint32_t u; } c; c.f = x;
    uint32_t r = c.u + 0x7fffu + ((c.u >> 16) & 1u);
    return (u16)(r >> 16);
}

// ---------------------------------------------------------------------------
// Row l2-normalize: in [rows,1024] f32 -> out [rows,1024] bf16. 1 block/row.
__global__ __launch_bounds__(256) void norm_rows_kernel(
        const float* __restrict__ in, u16* __restrict__ outn) {
    __shared__ float sred[4];
    const int row = blockIdx.x;
    const int t = threadIdx.x;
    const float4 v = ((const float4*)(in + (size_t)row * DK))[t];
    float ss = v.x * v.x + v.y * v.y + v.z * v.z + v.w * v.w;
#pragma unroll
    for (int o = 32; o > 0; o >>= 1) ss += __shfl_xor(ss, o);
    if ((t & 63) == 0) sred[t >> 6] = ss;
    __syncthreads();
    const float tot = sred[0] + sred[1] + sred[2] + sred[3];
    const float rs = 1.0f / fmaxf(sqrtf(tot), NORM_EPS);
    ushort4 o4;
    o4.x = f2bf(v.x * rs); o4.y = f2bf(v.y * rs);
    o4.z = f2bf(v.z * rs); o4.w = f2bf(v.w * rs);
    ((ushort4*)(outn + (size_t)row * DK))[t] = o4;
}

// ---------------------------------------------------------------------------
__global__ __launch_bounds__(256) void prep_scalars_kernel(
        const float* __restrict__ usage, float* __restrict__ hscaled,
        float* __restrict__ wsum) {
    const int g = blockIdx.x * 256 + threadIdx.x;
    if (g < GP) {
        hscaled[g] = logf(fmaxf(usage[g], EPS)) * INV_TEMP;
        wsum[g] = 0.0f;
    }
}

// ---------------------------------------------------------------------------
// Transpose f32 [R,C] -> bf16 [C,R].  64x64 tiles, LDS staged, +1 pad.
__global__ __launch_bounds__(256) void transpose_f32_bf16_kernel(
        const float* __restrict__ in, u16* __restrict__ out, int R, int C) {
    __shared__ float tile[64][65];
    const int r0 = blockIdx.x * 64;
    const int c0 = blockIdx.y * 64;
    const int t = threadIdx.x;
    const int lr = t >> 4;            // 0..15
    const int lc = (t & 15) << 2;     // 0..60
#pragma unroll
    for (int i = 0; i < 4; ++i) {
        float4 v = *(const float4*)(in + (size_t)(r0 + lr + i * 16) * C + (c0 + lc));
        tile[lr + i * 16][lc + 0] = v.x;
        tile[lr + i * 16][lc + 1] = v.y;
        tile[lr + i * 16][lc + 2] = v.z;
        tile[lr + i * 16][lc + 3] = v.w;
    }
    __syncthreads();
    const int oc = t >> 2;            // 0..63  (output row = original col)
    const int rseg = (t & 3) << 4;    // 0,16,32,48
    __align__(16) u16 tmp[16];
#pragma unroll
    for (int j = 0; j < 16; ++j) tmp[j] = f2bf(tile[rseg + j][oc]);
    u16* op = out + (size_t)(c0 + oc) * R + (r0 + rseg);
    ((uint4*)op)[0] = ((const uint4*)tmp)[0];
    ((uint4*)op)[1] = ((const uint4*)tmp)[1];
}

// ---------------------------------------------------------------------------
// Shared 128x128 bt-GEMM mainloop: A [Ma,K], B [Nb,K] row-major bf16 (as u16).
// 256 threads = 4 waves in 2x2; each wave 64x64 = 4x4 frags of 16x16x32 MFMA.
template <int K>
__device__ inline void gemm_bt_tile(const u16* __restrict__ A,
                                    const u16* __restrict__ B,
                                    int m0, int n0,
                                    u16* As, u16* Bs, f32x4 acc[4][4]) {
    const int t = threadIdx.x;
    const int lane = t & 63;
    const int wave = t >> 6;
    const int wm = (wave >> 1) * 64;
    const int wn = (wave & 1) * 64;
    const int fr = lane & 15;            // frag row (m for A, n for B)
    const int ko = (lane >> 4) * 8;      // frag k offset (A[m][k]: k = quad*8+j)

#pragma unroll 1
    for (int kt = 0; kt < K; kt += 64) {
        __syncthreads();   // protect previous iter's frag reads
        // stage A,B 128x64 bf16 tiles: 1024 16B-units each; 4 units/thread each
#pragma unroll
        for (int i = 0; i < 4; ++i) {
            const int u = t + i * 256;
            const int r = u >> 3;
            const int c = (u & 7) << 3;  // bf16 elem offset in row
            *(uint4*)(As + r * 64 + c) = *(const uint4*)(A + (size_t)(m0 + r) * K + kt + c);
            *(uint4*)(Bs + r * 64 + c) = *(const uint4*)(B + (size_t)(n0 + r) * K + kt + c);
        }
        __syncthreads();
#pragma unroll
        for (int ks = 0; ks < 64; ks += 32) {
            bf16x8 af[4], bfr[4];
#pragma unroll
            for (int f = 0; f < 4; ++f) {
                af[f]  = *(const bf16x8*)(As + (wm + f * 16 + fr) * 64 + ks + ko);
                bfr[f] = *(const bf16x8*)(Bs + (wn + f * 16 + fr) * 64 + ks + ko);
            }
#pragma unroll
            for (int fm = 0; fm < 4; ++fm)
#pragma unroll
                for (int fn = 0; fn < 4; ++fn)
                    acc[fm][fn] = __builtin_amdgcn_mfma_f32_16x16x32_bf16(
                        af[fm], bfr[fn], acc[fm][fn], 0, 0, 0);
        }
    }
}

// GEMM1: s[n][g] = (Q[n,:]·P[g,:])/T - hscaled[g]
__global__ __launch_bounds__(256) void gemm1_kernel(
        const u16* __restrict__ Q, const u16* __restrict__ P,
        const float* __restrict__ hs, float* __restrict__ Wout) {
    __shared__ u16 As[128 * 64];
    __shared__ u16 Bs[128 * 64];
    const int bid = blockIdx.x;
    const int m0 = (bid >> 5) * 128;    // 128 m-tiles (N rows)
    const int n0 = (bid & 31) * 128;    // 32 n-tiles (G)
    f32x4 acc[4][4];
#pragma unroll
    for (int a = 0; a < 4; ++a)
#pragma unroll
        for (int b = 0; b < 4; ++b) acc[a][b] = (f32x4){0.f, 0.f, 0.f, 0.f};
    gemm_bt_tile<DK>(Q, P, m0, n0, As, Bs, acc);

    const int lane = threadIdx.x & 63;
    const int wave = threadIdx.x >> 6;
    const int wm = (wave >> 1) * 64, wn = (wave & 1) * 64;
    const int cq = lane & 15, rq = (lane >> 4) * 4;   // C/D: col=lane&15, row=quad*4+reg
#pragma unroll
    for (int fn = 0; fn < 4; ++fn) {
        const int g = n0 + wn + fn * 16 + cq;
        const float h = hs[g];
#pragma unroll
        for (int fm = 0; fm < 4; ++fm) {
            const int mb = m0 + wm + fm * 16 + rq;
#pragma unroll
            for (int r = 0; r < 4; ++r)
                Wout[(size_t)(mb + r) * GP + g] = acc[fm][fn][r] * INV_TEMP - h;
        }
    }
}

// GEMM2: blended_pre[g][d] = DECAY*pat[g][d] + OMD * (acc[g][d] * invw[g])
__global__ __launch_bounds__(256) void gemm2_kernel(
        const u16* __restrict__ WT, const u16* __restrict__ FT,
        const float* __restrict__ invw, const float* __restrict__ patterns,
        float* __restrict__ Pout) {
    __shared__ u16 As[128 * 64];
    __shared__ u16 Bs[128 * 64];
    const int bid = blockIdx.x;
    const int n0 = (bid & 7) * 128;     // 8 d-tiles; bid%8 == XCD -> B strip L2-resident
    const int m0 = (bid >> 3) * 128;    // 32 g-tiles
    f32x4 acc[4][4];
#pragma unroll
    for (int a = 0; a < 4; ++a)
#pragma unroll
        for (int b = 0; b < 4; ++b) acc[a][b] = (f32x4){0.f, 0.f, 0.f, 0.f};
    gemm_bt_tile<NROWS>(WT, FT, m0, n0, As, Bs, acc);

    const int lane = threadIdx.x & 63;
    const int wave = threadIdx.x >> 6;
    const int wm = (wave >> 1) * 64, wn = (wave & 1) * 64;
    const int cq = lane & 15, rq = (lane >> 4) * 4;
#pragma unroll
    for (int fn = 0; fn < 4; ++fn) {
        const int d = n0 + wn + fn * 16 + cq;
#pragma unroll
        for (int fm = 0; fm < 4; ++fm) {
            const int gb = m0 + wm + fm * 16 + rq;
#pragma unroll
            for (int r = 0; r < 4; ++r) {
                const int g = gb + r;
                const float u = acc[fm][fn][r] * invw[g];
                const float pat = patterns[(size_t)g * DK + d];
                Pout[(size_t)g * DK + d] = DECAY * pat + OMD * u;
            }
        }
    }
}

// ---------------------------------------------------------------------------
// Softmax over rows of W [N,G] in-place + column-sum accumulation into wsum.
// 32 rows/block; thread t owns columns t+256*j (j=0..15) -> colsums in regs.
__global__ __launch_bounds__(256) void softmax_kernel(
        float* __restrict__ W, float* __restrict__ wsum) {
    __shared__ float sred[4];
    const int t = threadIdx.x;
    float csum[16];
#pragma unroll
    for (int j = 0; j < 16; ++j) csum[j] = 0.f;

    for (int r = 0; r < 32; ++r) {
        float* Wr = W + (size_t)(blockIdx.x * 32 + r) * GP;
        float v[16];
        float m = -INFINITY;
#pragma unroll
        for (int j = 0; j < 16; ++j) { v[j] = Wr[t + j * 256]; m = fmaxf(m, v[j]); }
#pragma unroll
        for (int o = 32; o > 0; o >>= 1) m = fmaxf(m, __shfl_xor(m, o));
        if ((t & 63) == 0) sred[t >> 6] = m;
        __syncthreads();
        m = fmaxf(fmaxf(sred[0], sred[1]), fmaxf(sred[2], sred[3]));
        __syncthreads();
        float s = 0.f;
#pragma unroll
        for (int j = 0; j < 16; ++j) { v[j] = __expf(v[j] - m); s += v[j]; }
#pragma unroll
        for (int o = 32; o > 0; o >>= 1) s += __shfl_xor(s, o);
        if ((t & 63) == 0) sred[t >> 6] = s;
        __syncthreads();
        s = sred[0] + sred[1] + sred[2] + sred[3];
        __syncthreads();
        const float inv = 1.0f / s;
#pragma unroll
        for (int j = 0; j < 16; ++j) {
            const float w = v[j] * inv;
            Wr[t + j * 256] = w;
            csum[j] += w;
        }
    }
#pragma unroll
    for (int j = 0; j < 16; ++j) atomicAdd(&wsum[t + j * 256], csum[j]);
}

// ---------------------------------------------------------------------------
__global__ __launch_bounds__(256) void usage_kernel(
        const float* __restrict__ usage, const float* __restrict__ wsum,
        float* __restrict__ Uout, float* __restrict__ invw) {
    const int g = blockIdx.x * 256 + threadIdx.x;
    if (g < GP) {
        const float s = wsum[g];
        Uout[g] = usage[g] * DECAY + (s > 0.f ? OMD * s : 0.f);
        invw[g] = 1.0f / (s + EPS);
    }
}

// Final row l2-norm of blended_pre (in Pout), fallback to patterns if !valid.
__global__ __launch_bounds__(256) void finalize_patterns_kernel(
        const float* __restrict__ patterns, const float* __restrict__ wsum,
        float* __restrict__ Pout) {
    __shared__ float sred[4];
    const int g = blockIdx.x;
    const int t = threadIdx.x;
    float4 b = ((const float4*)(Pout + (size_t)g * DK))[t];
    float ss = b.x * b.x + b.y * b.y + b.z * b.z + b.w * b.w;
#pragma unroll
    for (int o = 32; o > 0; o >>= 1) ss += __shfl_xor(ss, o);
    if ((t & 63) == 0) sred[t >> 6] = ss;
    __syncthreads();
    const float tot = sred[0] + sred[1] + sred[2] + sred[3];
    const float rs = 1.0f / fmaxf(sqrtf(tot), NORM_EPS);
    float4 o4;
    if (wsum[g] > 0.f) {
        o4.x = b.x * rs; o4.y = b.y * rs; o4.z = b.z * rs; o4.w = b.w * rs;
    } else {
        o4 = ((const float4*)(patterns + (size_t)g * DK))[t];
    }
    ((float4*)(Pout + (size_t)g * DK))[t] = o4;
}

// ---------------------------------------------------------------------------
extern "C" void kernel_launch(void* const* d_in, const int* in_sizes, int n_in,
                              void* d_out, int out_size, void* d_ws, size_t ws_size,
                              hipStream_t stream) {
    const float* pair_embed = (const float*)d_in[0];
    const float* patterns   = (const float*)d_in[1];
    const float* usage      = (const float*)d_in[2];

    float* out_w = (float*)d_out;                       // [16384,4096]
    float* out_p = out_w + (size_t)NROWS * GP;          // [4096,1024]
    float* out_u = out_p + (size_t)GP * DK;             // [4096]

    char* ws = (char*)d_ws;
    u16* q_bf   = (u16*)(ws);                            // 32 MiB  [16384,1024]
    u16* pat_bf = (u16*)(ws + 33554432);                 //  8 MiB  [4096,1024]
    u16* fT     = (u16*)(ws + 41943040);                 // 32 MiB  [1024,16384]
    u16* wT     = (u16*)(ws + 75497472);                 //128 MiB  [4096,16384]
    float* hs   = (float*)(ws + 209715200);              // 16 KiB
    float* wsum = (float*)(ws + 209715200 + 16384);      // 16 KiB
    float* invw = (float*)(ws + 209715200 + 32768);      // 16 KiB

    prep_scalars_kernel<<<16, 256, 0, stream>>>(usage, hs, wsum);
    norm_rows_kernel<<<NROWS, 256, 0, stream>>>(pair_embed, q_bf);
    norm_rows_kernel<<<GP, 256, 0, stream>>>(patterns, pat_bf);
    {   // flat^T -> bf16 [1024,16384]
        dim3 g(NROWS / 64, DK / 64);
        transpose_f32_bf16_kernel<<<g, 256, 0, stream>>>(pair_embed, fT, NROWS, DK);
    }
    gemm1_kernel<<<(NROWS / 128) * (GP / 128), 256, 0, stream>>>(q_bf, pat_bf, hs, out_w);
    softmax_kernel<<<NROWS / 32, 256, 0, stream>>>(out_w, wsum);
    usage_kernel<<<16, 256, 0, stream>>>(usage, wsum, out_u, invw);
    {   // weights^T -> bf16 [4096,16384]
        dim3 g(NROWS / 64, GP / 64);
        transpose_f32_bf16_kernel<<<g, 256, 0, stream>>>(out_w, wT, NROWS, GP);
    }
    gemm2_kernel<<<(GP / 128) * (DK / 128), 256, 0, stream>>>(wT, fT, invw, patterns, out_p);
    finalize_patterns_kernel<<<GP, 256, 0, stream>>>(patterns, wsum, out_p);
}

// Round 2
// 1045.068 us; speedup vs baseline: 1.1503x; 1.1503x over previous
//
#include <hip/hip_runtime.h>
#include <stdint.h>
#include <math.h>

// ---------------------------------------------------------------------------
// HebbianGroupMemory on MI355X (gfx950)
//   pair_embed [8,2048,1024] f32  -> flat [N=16384, D=1024]
//   patterns   [G=4096, D=1024] f32
//   usage      [G=4096] f32
// Outputs (concat f32): weights [16384,4096], patterns_new [4096,1024], usage_new [4096]
//
// R1 changes:
//  - gemm2 split-K 8x (grid 256 -> 2048 blocks; was 1 block/CU, occupancy 11%)
//    partials atomicAdd into f32 Upart; scale/blend moved to finalize.
//  - LDS K-stride padded 64 -> 72 bf16 (144 B): kills the 16-lane/4-bank
//    aliasing (SQ_LDS_BANK_CONFLICT 5e7 in R1).
//  - softmax float4 ownership (4x wider global access).
//  - Upart aliases dead q_bf region (stream-ordered, gemm1 done) -> ws same size.
// ---------------------------------------------------------------------------

#define DECAY 0.97f
#define OMD 0.03f                 // 1 - DECAY
#define INV_TEMP (1.0f / 0.7f)
#define EPS 1e-6f
#define NORM_EPS 1e-12f

constexpr int NROWS = 16384;      // 8*2048
constexpr int DK = 1024;
constexpr int GP = 4096;
constexpr int LDSK = 72;          // padded LDS K-stride (bf16 elems); 144 B

typedef unsigned short u16;
typedef __bf16 bf16x8 __attribute__((ext_vector_type(8)));   // MFMA A/B operand
typedef float f32x4 __attribute__((ext_vector_type(4)));      // MFMA C/D

// round-to-nearest-even f32 -> bf16 (as raw u16)
__device__ inline u16 f2bf(float x) {
    union { float f; uint32_t u; } c; c.f = x;
    uint32_t r = c.u + 0x7fffu + ((c.u >> 16) & 1u);
    return (u16)(r >> 16);
}

// ---------------------------------------------------------------------------
// Row l2-normalize: in [rows,1024] f32 -> out [rows,1024] bf16. 1 block/row.
__global__ __launch_bounds__(256) void norm_rows_kernel(
        const float* __restrict__ in, u16* __restrict__ outn) {
    __shared__ float sred[4];
    const int row = blockIdx.x;
    const int t = threadIdx.x;
    const float4 v = ((const float4*)(in + (size_t)row * DK))[t];
    float ss = v.x * v.x + v.y * v.y + v.z * v.z + v.w * v.w;
#pragma unroll
    for (int o = 32; o > 0; o >>= 1) ss += __shfl_xor(ss, o);
    if ((t & 63) == 0) sred[t >> 6] = ss;
    __syncthreads();
    const float tot = sred[0] + sred[1] + sred[2] + sred[3];
    const float rs = 1.0f / fmaxf(sqrtf(tot), NORM_EPS);
    ushort4 o4;
    o4.x = f2bf(v.x * rs); o4.y = f2bf(v.y * rs);
    o4.z = f2bf(v.z * rs); o4.w = f2bf(v.w * rs);
    ((ushort4*)(outn + (size_t)row * DK))[t] = o4;
}

// ---------------------------------------------------------------------------
__global__ __launch_bounds__(256) void prep_scalars_kernel(
        const float* __restrict__ usage, float* __restrict__ hscaled,
        float* __restrict__ wsum) {
    const int g = blockIdx.x * 256 + threadIdx.x;
    if (g < GP) {
        hscaled[g] = logf(fmaxf(usage[g], EPS)) * INV_TEMP;
        wsum[g] = 0.0f;
    }
}

__global__ __launch_bounds__(256) void zero_kernel(float4* __restrict__ p) {
    p[(size_t)blockIdx.x * 256 + threadIdx.x] = (float4){0.f, 0.f, 0.f, 0.f};
}

// ---------------------------------------------------------------------------
// Transpose f32 [R,C] -> bf16 [C,R].  64x64 tiles, LDS staged, +1 pad.
__global__ __launch_bounds__(256) void transpose_f32_bf16_kernel(
        const float* __restrict__ in, u16* __restrict__ out, int R, int C) {
    __shared__ float tile[64][65];
    const int r0 = blockIdx.x * 64;
    const int c0 = blockIdx.y * 64;
    const int t = threadIdx.x;
    const int lr = t >> 4;            // 0..15
    const int lc = (t & 15) << 2;     // 0..60
#pragma unroll
    for (int i = 0; i < 4; ++i) {
        float4 v = *(const float4*)(in + (size_t)(r0 + lr + i * 16) * C + (c0 + lc));
        tile[lr + i * 16][lc + 0] = v.x;
        tile[lr + i * 16][lc + 1] = v.y;
        tile[lr + i * 16][lc + 2] = v.z;
        tile[lr + i * 16][lc + 3] = v.w;
    }
    __syncthreads();
    const int oc = t >> 2;            // 0..63  (output row = original col)
    const int rseg = (t & 3) << 4;    // 0,16,32,48
    __align__(16) u16 tmp[16];
#pragma unroll
    for (int j = 0; j < 16; ++j) tmp[j] = f2bf(tile[rseg + j][oc]);
    u16* op = out + (size_t)(c0 + oc) * R + (r0 + rseg);
    ((uint4*)op)[0] = ((const uint4*)tmp)[0];
    ((uint4*)op)[1] = ((const uint4*)tmp)[1];
}

// ---------------------------------------------------------------------------
// Shared 128x128 bt-GEMM mainloop: A [*,KLD], B [*,KLD] row-major bf16 (u16).
// Iterates K range [k0, k0+KSTEPS). 256 threads = 4 waves in 2x2; each wave
// 64x64 = 4x4 frags of 16x16x32 MFMA. LDS rows padded to LDSK=72 elems.
template <int KSTEPS, int KLD>
__device__ inline void gemm_bt_tile(const u16* __restrict__ A,
                                    const u16* __restrict__ B,
                                    int m0, int n0, int k0,
                                    u16* As, u16* Bs, f32x4 acc[4][4]) {
    const int t = threadIdx.x;
    const int lane = t & 63;
    const int wave = t >> 6;
    const int wm = (wave >> 1) * 64;
    const int wn = (wave & 1) * 64;
    const int fr = lane & 15;            // frag row (m for A, n for B)
    const int ko = (lane >> 4) * 8;      // frag k offset

#pragma unroll 1
    for (int kt = 0; kt < KSTEPS; kt += 64) {
        __syncthreads();   // protect previous iter's frag reads
        // stage A,B 128x64 bf16 tiles: 1024 16B-units each; 4 units/thread each
#pragma unroll
        for (int i = 0; i < 4; ++i) {
            const int u = t + i * 256;
            const int r = u >> 3;
            const int c = (u & 7) << 3;  // bf16 elem offset in row
            *(uint4*)(As + r * LDSK + c) =
                *(const uint4*)(A + (size_t)(m0 + r) * KLD + k0 + kt + c);
            *(uint4*)(Bs + r * LDSK + c) =
                *(const uint4*)(B + (size_t)(n0 + r) * KLD + k0 + kt + c);
        }
        __syncthreads();
#pragma unroll
        for (int ks = 0; ks < 64; ks += 32) {
            bf16x8 af[4], bfr[4];
#pragma unroll
            for (int f = 0; f < 4; ++f) {
                af[f]  = *(const bf16x8*)(As + (wm + f * 16 + fr) * LDSK + ks + ko);
                bfr[f] = *(const bf16x8*)(Bs + (wn + f * 16 + fr) * LDSK + ks + ko);
            }
#pragma unroll
            for (int fm = 0; fm < 4; ++fm)
#pragma unroll
                for (int fn = 0; fn < 4; ++fn)
                    acc[fm][fn] = __builtin_amdgcn_mfma_f32_16x16x32_bf16(
                        af[fm], bfr[fn], acc[fm][fn], 0, 0, 0);
        }
    }
}

// GEMM1: s[n][g] = (Q[n,:]·P[g,:])/T - hscaled[g]
__global__ __launch_bounds__(256) void gemm1_kernel(
        const u16* __restrict__ Q, const u16* __restrict__ P,
        const float* __restrict__ hs, float* __restrict__ Wout) {
    __shared__ u16 As[128 * LDSK];
    __shared__ u16 Bs[128 * LDSK];
    const int bid = blockIdx.x;
    const int m0 = (bid >> 5) * 128;    // 128 m-tiles (N rows)
    const int n0 = (bid & 31) * 128;    // 32 n-tiles (G)
    f32x4 acc[4][4];
#pragma unroll
    for (int a = 0; a < 4; ++a)
#pragma unroll
        for (int b = 0; b < 4; ++b) acc[a][b] = (f32x4){0.f, 0.f, 0.f, 0.f};
    gemm_bt_tile<DK, DK>(Q, P, m0, n0, 0, As, Bs, acc);

    const int lane = threadIdx.x & 63;
    const int wave = threadIdx.x >> 6;
    const int wm = (wave >> 1) * 64, wn = (wave & 1) * 64;
    const int cq = lane & 15, rq = (lane >> 4) * 4;   // C/D: col=lane&15, row=quad*4+reg
#pragma unroll
    for (int fn = 0; fn < 4; ++fn) {
        const int g = n0 + wn + fn * 16 + cq;
        const float h = hs[g];
#pragma unroll
        for (int fm = 0; fm < 4; ++fm) {
            const int mb = m0 + wm + fm * 16 + rq;
#pragma unroll
            for (int r = 0; r < 4; ++r)
                Wout[(size_t)(mb + r) * GP + g] = acc[fm][fn][r] * INV_TEMP - h;
        }
    }
}

// GEMM2 (split-K): Upart[g][d] += sum over K-slice of WT[g,:]·FT[d,:]
__global__ __launch_bounds__(256) void gemm2_kernel(
        const u16* __restrict__ WT, const u16* __restrict__ FT,
        float* __restrict__ Upart) {
    __shared__ u16 As[128 * LDSK];
    __shared__ u16 Bs[128 * LDSK];
    const int bid = blockIdx.x;
    const int n0 = (bid & 7) * 128;          // 8 d-tiles; bid%8 -> XCD locality on FT strip
    const int m0 = ((bid >> 3) & 31) * 128;  // 32 g-tiles
    const int k0 = (bid >> 8) * 2048;        // 8 K-slices
    f32x4 acc[4][4];
#pragma unroll
    for (int a = 0; a < 4; ++a)
#pragma unroll
        for (int b = 0; b < 4; ++b) acc[a][b] = (f32x4){0.f, 0.f, 0.f, 0.f};
    gemm_bt_tile<2048, NROWS>(WT, FT, m0, n0, k0, As, Bs, acc);

    const int lane = threadIdx.x & 63;
    const int wave = threadIdx.x >> 6;
    const int wm = (wave >> 1) * 64, wn = (wave & 1) * 64;
    const int cq = lane & 15, rq = (lane >> 4) * 4;
#pragma unroll
    for (int fn = 0; fn < 4; ++fn) {
        const int d = n0 + wn + fn * 16 + cq;
#pragma unroll
        for (int fm = 0; fm < 4; ++fm) {
            const int gb = m0 + wm + fm * 16 + rq;
#pragma unroll
            for (int r = 0; r < 4; ++r)
                atomicAdd(&Upart[(size_t)(gb + r) * DK + d], acc[fm][fn][r]);
        }
    }
}

// ---------------------------------------------------------------------------
// Softmax over rows of W [N,G] in-place + column-sum accumulation into wsum.
// 32 rows/block; thread t owns float4 columns 4t+1024j (j=0..3).
__global__ __launch_bounds__(256) void softmax_kernel(
        float* __restrict__ W, float* __restrict__ wsum) {
    __shared__ float sred[4];
    const int t = threadIdx.x;
    float cs[4][4];
#pragma unroll
    for (int j = 0; j < 4; ++j)
#pragma unroll
        for (int i = 0; i < 4; ++i) cs[j][i] = 0.f;

    for (int r = 0; r < 32; ++r) {
        float4* Wr = (float4*)(W + (size_t)(blockIdx.x * 32 + r) * GP);
        float4 v[4];
        float m = -INFINITY;
#pragma unroll
        for (int j = 0; j < 4; ++j) {
            v[j] = Wr[t + j * 256];
            m = fmaxf(m, fmaxf(fmaxf(v[j].x, v[j].y), fmaxf(v[j].z, v[j].w)));
        }
#pragma unroll
        for (int o = 32; o > 0; o >>= 1) m = fmaxf(m, __shfl_xor(m, o));
        if ((t & 63) == 0) sred[t >> 6] = m;
        __syncthreads();
        m = fmaxf(fmaxf(sred[0], sred[1]), fmaxf(sred[2], sred[3]));
        __syncthreads();
        float s = 0.f;
#pragma unroll
        for (int j = 0; j < 4; ++j) {
            v[j].x = __expf(v[j].x - m); v[j].y = __expf(v[j].y - m);
            v[j].z = __expf(v[j].z - m); v[j].w = __expf(v[j].w - m);
            s += v[j].x + v[j].y + v[j].z + v[j].w;
        }
#pragma unroll
        for (int o = 32; o > 0; o >>= 1) s += __shfl_xor(s, o);
        if ((t & 63) == 0) sred[t >> 6] = s;
        __syncthreads();
        s = sred[0] + sred[1] + sred[2] + sred[3];
        __syncthreads();
        const float inv = 1.0f / s;
#pragma unroll
        for (int j = 0; j < 4; ++j) {
            v[j].x *= inv; v[j].y *= inv; v[j].z *= inv; v[j].w *= inv;
            Wr[t + j * 256] = v[j];
            cs[j][0] += v[j].x; cs[j][1] += v[j].y;
            cs[j][2] += v[j].z; cs[j][3] += v[j].w;
        }
    }
#pragma unroll
    for (int j = 0; j < 4; ++j)
#pragma unroll
        for (int i = 0; i < 4; ++i)
            atomicAdd(&wsum[4 * t + 1024 * j + i], cs[j][i]);
}

// ---------------------------------------------------------------------------
__global__ __launch_bounds__(256) void usage_kernel(
        const float* __restrict__ usage, const float* __restrict__ wsum,
        float* __restrict__ Uout, float* __restrict__ invw) {
    const int g = blockIdx.x * 256 + threadIdx.x;
    if (g < GP) {
        const float s = wsum[g];
        Uout[g] = usage[g] * DECAY + (s > 0.f ? OMD * s : 0.f);
        invw[g] = 1.0f / (s + EPS);
    }
}

// Final: blended = l2norm(DECAY*pat + OMD*Upart*invw[g]); fallback if !valid.
__global__ __launch_bounds__(256) void finalize_patterns_kernel(
        const float* __restrict__ patterns, const float* __restrict__ wsum,
        const float* __restrict__ invw, const float* __restrict__ Upart,
        float* __restrict__ Pout) {
    __shared__ float sred[4];
    const int g = blockIdx.x;
    const int t = threadIdx.x;
    const float iw = invw[g] * OMD;
    const float4 u4 = ((const float4*)(Upart + (size_t)g * DK))[t];
    const float4 p4 = ((const float4*)(patterns + (size_t)g * DK))[t];
    float4 b;
    b.x = DECAY * p4.x + iw * u4.x;
    b.y = DECAY * p4.y + iw * u4.y;
    b.z = DECAY * p4.z + iw * u4.z;
    b.w = DECAY * p4.w + iw * u4.w;
    float ss = b.x * b.x + b.y * b.y + b.z * b.z + b.w * b.w;
#pragma unroll
    for (int o = 32; o > 0; o >>= 1) ss += __shfl_xor(ss, o);
    if ((t & 63) == 0) sred[t >> 6] = ss;
    __syncthreads();
    const float tot = sred[0] + sred[1] + sred[2] + sred[3];
    const float rs = 1.0f / fmaxf(sqrtf(tot), NORM_EPS);
    float4 o4;
    if (wsum[g] > 0.f) {
        o4.x = b.x * rs; o4.y = b.y * rs; o4.z = b.z * rs; o4.w = b.w * rs;
    } else {
        o4 = p4;
    }
    ((float4*)(Pout + (size_t)g * DK))[t] = o4;
}

// ---------------------------------------------------------------------------
extern "C" void kernel_launch(void* const* d_in, const int* in_sizes, int n_in,
                              void* d_out, int out_size, void* d_ws, size_t ws_size,
                              hipStream_t stream) {
    const float* pair_embed = (const float*)d_in[0];
    const float* patterns   = (const float*)d_in[1];
    const float* usage      = (const float*)d_in[2];

    float* out_w = (float*)d_out;                       // [16384,4096]
    float* out_p = out_w + (size_t)NROWS * GP;          // [4096,1024]
    float* out_u = out_p + (size_t)GP * DK;             // [4096]

    char* ws = (char*)d_ws;
    u16* q_bf   = (u16*)(ws);                            // 32 MiB [16384,1024]; dead after gemm1
    float* Upart = (float*)(ws);                         // 16 MiB [4096,1024] (aliases q_bf)
    u16* pat_bf = (u16*)(ws + 33554432);                 //  8 MiB [4096,1024]
    u16* fT     = (u16*)(ws + 41943040);                 // 32 MiB [1024,16384]
    u16* wT     = (u16*)(ws + 75497472);                 //128 MiB [4096,16384]
    float* hs   = (float*)(ws + 209715200);              // 16 KiB
    float* wsum = (float*)(ws + 209715200 + 16384);      // 16 KiB
    float* invw = (float*)(ws + 209715200 + 32768);      // 16 KiB

    prep_scalars_kernel<<<16, 256, 0, stream>>>(usage, hs, wsum);
    norm_rows_kernel<<<NROWS, 256, 0, stream>>>(pair_embed, q_bf);
    norm_rows_kernel<<<GP, 256, 0, stream>>>(patterns, pat_bf);
    {   // flat^T -> bf16 [1024,16384]
        dim3 g(NROWS / 64, DK / 64);
        transpose_f32_bf16_kernel<<<g, 256, 0, stream>>>(pair_embed, fT, NROWS, DK);
    }
    gemm1_kernel<<<(NROWS / 128) * (GP / 128), 256, 0, stream>>>(q_bf, pat_bf, hs, out_w);
    softmax_kernel<<<NROWS / 32, 256, 0, stream>>>(out_w, wsum);
    usage_kernel<<<16, 256, 0, stream>>>(usage, wsum, out_u, invw);
    // q_bf dead from here on; reuse its space as Upart (stream-ordered).
    zero_kernel<<<(GP * DK / 4) / 256, 256, 0, stream>>>((float4*)Upart);
    {   // weights^T -> bf16 [4096,16384]
        dim3 g(NROWS / 64, GP / 64);
        transpose_f32_bf16_kernel<<<g, 256, 0, stream>>>(out_w, wT, NROWS, GP);
    }
    gemm2_kernel<<<8 * (GP / 128) * (DK / 128), 256, 0, stream>>>(wT, fT, Upart);
    finalize_patterns_kernel<<<GP, 256, 0, stream>>>(patterns, wsum, invw, Upart, out_p);
}

// Round 3
// 968.719 us; speedup vs baseline: 1.2410x; 1.0788x over previous
//
#include <hip/hip_runtime.h>
#include <stdint.h>
#include <math.h>

// ---------------------------------------------------------------------------
// HebbianGroupMemory on MI355X (gfx950)
//   pair_embed [8,2048,1024] f32  -> flat [N=16384, D=1024]
//   patterns   [G=4096, D=1024] f32
//   usage      [G=4096] f32
// Outputs (concat f32): weights [16384,4096], patterns_new [4096,1024], usage_new [4096]
//
// R2 changes:
//  - GEMM staging via __builtin_amdgcn_global_load_lds (16B) -- no VGPR
//    round-trip (m93->m97 was 517->874 TF for exactly this change).
//  - LDS tile unpadded (required: global_load_lds dest = base + lane*16) with
//    XOR k-octet swizzle: lane fetches global octet (l&7)^(row&7); frag reads
//    invert. ds_read_b128 spreads 2 lanes/bank-group = conflict-free.
//  - gemm2 block swizzle: k-slice = bid&7 (XCD key) so each XCD streams one
//    K-slice through its own L2.
//  - transpose rewritten 64x256 tiles: each thread writes one 128B-contiguous
//    output row chunk (was 32B scattered).
// ---------------------------------------------------------------------------

#define DECAY 0.97f
#define OMD 0.03f                 // 1 - DECAY
#define INV_TEMP (1.0f / 0.7f)
#define EPS 1e-6f
#define NORM_EPS 1e-12f

constexpr int NROWS = 16384;      // 8*2048
constexpr int DK = 1024;
constexpr int GP = 4096;

typedef unsigned short u16;
typedef __bf16 bf16x8 __attribute__((ext_vector_type(8)));   // MFMA A/B operand
typedef float f32x4 __attribute__((ext_vector_type(4)));      // MFMA C/D

// round-to-nearest-even f32 -> bf16 (as raw u16)
__device__ inline u16 f2bf(float x) {
    union { float f; uint32_t u; } c; c.f = x;
    uint32_t r = c.u + 0x7fffu + ((c.u >> 16) & 1u);
    return (u16)(r >> 16);
}

// async global->LDS, 16 bytes/lane; LDS dest = wave-uniform base + lane*16
__device__ inline void gl_lds16(const u16* g, u16* l) {
    __builtin_amdgcn_global_load_lds(
        (const __attribute__((address_space(1))) void*)g,
        (__attribute__((address_space(3))) void*)l, 16, 0, 0);
}

// ---------------------------------------------------------------------------
// Row l2-normalize: in [rows,1024] f32 -> out [rows,1024] bf16. 1 block/row.
__global__ __launch_bounds__(256) void norm_rows_kernel(
        const float* __restrict__ in, u16* __restrict__ outn) {
    __shared__ float sred[4];
    const int row = blockIdx.x;
    const int t = threadIdx.x;
    const float4 v = ((const float4*)(in + (size_t)row * DK))[t];
    float ss = v.x * v.x + v.y * v.y + v.z * v.z + v.w * v.w;
#pragma unroll
    for (int o = 32; o > 0; o >>= 1) ss += __shfl_xor(ss, o);
    if ((t & 63) == 0) sred[t >> 6] = ss;
    __syncthreads();
    const float tot = sred[0] + sred[1] + sred[2] + sred[3];
    const float rs = 1.0f / fmaxf(sqrtf(tot), NORM_EPS);
    ushort4 o4;
    o4.x = f2bf(v.x * rs); o4.y = f2bf(v.y * rs);
    o4.z = f2bf(v.z * rs); o4.w = f2bf(v.w * rs);
    ((ushort4*)(outn + (size_t)row * DK))[t] = o4;
}

// ---------------------------------------------------------------------------
__global__ __launch_bounds__(256) void prep_scalars_kernel(
        const float* __restrict__ usage, float* __restrict__ hscaled,
        float* __restrict__ wsum) {
    const int g = blockIdx.x * 256 + threadIdx.x;
    if (g < GP) {
        hscaled[g] = logf(fmaxf(usage[g], EPS)) * INV_TEMP;
        wsum[g] = 0.0f;
    }
}

__global__ __launch_bounds__(256) void zero_kernel(float4* __restrict__ p) {
    p[(size_t)blockIdx.x * 256 + threadIdx.x] = (float4){0.f, 0.f, 0.f, 0.f};
}

// ---------------------------------------------------------------------------
// Transpose f32 [R,C] -> bf16 [C,R].  64(r) x 256(c) tiles.
// Load: coalesced float4. Store: thread t owns output row c0+t, writes a
// 128B-contiguous chunk of 64 bf16. LDS rows padded to 260 floats:
// f4-store groups uniform (8 lanes/group), scalar reads 2-way (free).
__global__ __launch_bounds__(256) void transpose_f32_bf16_kernel(
        const float* __restrict__ in, u16* __restrict__ out, int R, int C) {
    __shared__ float tile[64][260];
    const int r0 = blockIdx.x * 64;
    const int c0 = blockIdx.y * 256;
    const int t = threadIdx.x;
    const int fr = t & 63;            // float4-col (cols c0 + fr*4)
    const int rr = t >> 6;            // row base 0..3
#pragma unroll
    for (int j = 0; j < 16; ++j) {
        const int r = rr + 4 * j;
        const float4 v = *(const float4*)(in + (size_t)(r0 + r) * C + c0 + fr * 4);
        *(float4*)&tile[r][fr * 4] = v;
    }
    __syncthreads();
    __align__(16) u16 tmp[64];
#pragma unroll
    for (int r = 0; r < 64; ++r) tmp[r] = f2bf(tile[r][t]);
    u16* op = out + (size_t)(c0 + t) * R + r0;
#pragma unroll
    for (int i = 0; i < 8; ++i) ((uint4*)op)[i] = ((const uint4*)tmp)[i];
}

// ---------------------------------------------------------------------------
// Shared 128x128 bt-GEMM mainloop: A [*,KLD], B [*,KLD] row-major bf16 (u16).
// K range [k0, k0+KSTEPS). 256 threads = 4 waves in 2x2; each wave 64x64 =
// 4x4 frags of 16x16x32 MFMA. LDS tiles 128x64 unpadded, staged by
// global_load_lds (16B/lane, wave stages 8 rows/issue, 4 issues/operand).
// XOR swizzle: physical octet p of row r holds logical octet p^(r&7).
template <int KSTEPS, int KLD>
__device__ inline void gemm_bt_tile(const u16* __restrict__ A,
                                    const u16* __restrict__ B,
                                    int m0, int n0, int k0,
                                    u16* As, u16* Bs, f32x4 acc[4][4]) {
    const int t = threadIdx.x;
    const int lane = t & 63;
    const int wave = t >> 6;
    const int wm = (wave >> 1) * 64;
    const int wn = (wave & 1) * 64;
    const int fr = lane & 15;            // frag row (m for A, n for B)
    const int q8 = lane >> 4;            // quad: k-octet index component

    // staging: lane covers tile row 32*wave + 8*i + (lane>>3),
    // global k-octet (lane&7)^(row&7); LDS slot auto = base + lane*16B.
    const int srow = 32 * wave + (lane >> 3);
    const int soct = (lane & 7) ^ ((lane >> 3) & 7);
    const size_t a_base = (size_t)(m0 + srow) * KLD + k0 + soct * 8;
    const size_t b_base = (size_t)(n0 + srow) * KLD + k0 + soct * 8;

#pragma unroll 1
    for (int kt = 0; kt < KSTEPS; kt += 64) {
        __syncthreads();   // protect previous iter's frag reads
#pragma unroll
        for (int i = 0; i < 4; ++i) {
            gl_lds16(A + a_base + (size_t)(8 * i) * KLD + kt,
                     As + (32 * wave + 8 * i) * 64);
            gl_lds16(B + b_base + (size_t)(8 * i) * KLD + kt,
                     Bs + (32 * wave + 8 * i) * 64);
        }
        __syncthreads();   // drains vmcnt (compiler emits full waitcnt)
#pragma unroll
        for (int ks8 = 0; ks8 < 8; ks8 += 4) {     // two k-steps of 32
            bf16x8 af[4], bfr[4];
#pragma unroll
            for (int f = 0; f < 4; ++f) {
                const int ra = wm + f * 16 + fr;
                af[f]  = *(const bf16x8*)(As + ra * 64 + (((ks8 + q8) ^ (ra & 7)) * 8));
                const int rb = wn + f * 16 + fr;
                bfr[f] = *(const bf16x8*)(Bs + rb * 64 + (((ks8 + q8) ^ (rb & 7)) * 8));
            }
#pragma unroll
            for (int fm = 0; fm < 4; ++fm)
#pragma unroll
                for (int fn = 0; fn < 4; ++fn)
                    acc[fm][fn] = __builtin_amdgcn_mfma_f32_16x16x32_bf16(
                        af[fm], bfr[fn], acc[fm][fn], 0, 0, 0);
        }
    }
}

// GEMM1: s[n][g] = (Q[n,:]·P[g,:])/T - hscaled[g]
__global__ __launch_bounds__(256) void gemm1_kernel(
        const u16* __restrict__ Q, const u16* __restrict__ P,
        const float* __restrict__ hs, float* __restrict__ Wout) {
    __shared__ u16 As[128 * 64];
    __shared__ u16 Bs[128 * 64];
    const int bid = blockIdx.x;
    const int m0 = (bid >> 5) * 128;    // 128 m-tiles (N rows)
    const int n0 = (bid & 31) * 128;    // 32 n-tiles (G)
    f32x4 acc[4][4];
#pragma unroll
    for (int a = 0; a < 4; ++a)
#pragma unroll
        for (int b = 0; b < 4; ++b) acc[a][b] = (f32x4){0.f, 0.f, 0.f, 0.f};
    gemm_bt_tile<DK, DK>(Q, P, m0, n0, 0, As, Bs, acc);

    const int lane = threadIdx.x & 63;
    const int wave = threadIdx.x >> 6;
    const int wm = (wave >> 1) * 64, wn = (wave & 1) * 64;
    const int cq = lane & 15, rq = (lane >> 4) * 4;   // C/D: col=lane&15, row=quad*4+reg
#pragma unroll
    for (int fn = 0; fn < 4; ++fn) {
        const int g = n0 + wn + fn * 16 + cq;
        const float h = hs[g];
#pragma unroll
        for (int fm = 0; fm < 4; ++fm) {
            const int mb = m0 + wm + fm * 16 + rq;
#pragma unroll
            for (int r = 0; r < 4; ++r)
                Wout[(size_t)(mb + r) * GP + g] = acc[fm][fn][r] * INV_TEMP - h;
        }
    }
}

// GEMM2 (split-K): Upart[g][d] += sum over K-slice of WT[g,:]·FT[d,:]
__global__ __launch_bounds__(256) void gemm2_kernel(
        const u16* __restrict__ WT, const u16* __restrict__ FT,
        float* __restrict__ Upart) {
    __shared__ u16 As[128 * 64];
    __shared__ u16 Bs[128 * 64];
    const int bid = blockIdx.x;
    const int k0 = (bid & 7) * 2048;         // k-slice = XCD key: per-XCD L2 strip
    const int n0 = ((bid >> 3) & 7) * 128;   // 8 d-tiles
    const int m0 = (bid >> 6) * 128;         // 32 g-tiles
    f32x4 acc[4][4];
#pragma unroll
    for (int a = 0; a < 4; ++a)
#pragma unroll
        for (int b = 0; b < 4; ++b) acc[a][b] = (f32x4){0.f, 0.f, 0.f, 0.f};
    gemm_bt_tile<2048, NROWS>(WT, FT, m0, n0, k0, As, Bs, acc);

    const int lane = threadIdx.x & 63;
    const int wave = threadIdx.x >> 6;
    const int wm = (wave >> 1) * 64, wn = (wave & 1) * 64;
    const int cq = lane & 15, rq = (lane >> 4) * 4;
#pragma unroll
    for (int fn = 0; fn < 4; ++fn) {
        const int d = n0 + wn + fn * 16 + cq;
#pragma unroll
        for (int fm = 0; fm < 4; ++fm) {
            const int gb = m0 + wm + fm * 16 + rq;
#pragma unroll
            for (int r = 0; r < 4; ++r)
                atomicAdd(&Upart[(size_t)(gb + r) * DK + d], acc[fm][fn][r]);
        }
    }
}

// ---------------------------------------------------------------------------
// Softmax over rows of W [N,G] in-place + column-sum accumulation into wsum.
// 32 rows/block; thread t owns float4 columns 4t+1024j (j=0..3).
__global__ __launch_bounds__(256) void softmax_kernel(
        float* __restrict__ W, float* __restrict__ wsum) {
    __shared__ float sred[4];
    const int t = threadIdx.x;
    float cs[4][4];
#pragma unroll
    for (int j = 0; j < 4; ++j)
#pragma unroll
        for (int i = 0; i < 4; ++i) cs[j][i] = 0.f;

    for (int r = 0; r < 32; ++r) {
        float4* Wr = (float4*)(W + (size_t)(blockIdx.x * 32 + r) * GP);
        float4 v[4];
        float m = -INFINITY;
#pragma unroll
        for (int j = 0; j < 4; ++j) {
            v[j] = Wr[t + j * 256];
            m = fmaxf(m, fmaxf(fmaxf(v[j].x, v[j].y), fmaxf(v[j].z, v[j].w)));
        }
#pragma unroll
        for (int o = 32; o > 0; o >>= 1) m = fmaxf(m, __shfl_xor(m, o));
        if ((t & 63) == 0) sred[t >> 6] = m;
        __syncthreads();
        m = fmaxf(fmaxf(sred[0], sred[1]), fmaxf(sred[2], sred[3]));
        __syncthreads();
        float s = 0.f;
#pragma unroll
        for (int j = 0; j < 4; ++j) {
            v[j].x = __expf(v[j].x - m); v[j].y = __expf(v[j].y - m);
            v[j].z = __expf(v[j].z - m); v[j].w = __expf(v[j].w - m);
            s += v[j].x + v[j].y + v[j].z + v[j].w;
        }
#pragma unroll
        for (int o = 32; o > 0; o >>= 1) s += __shfl_xor(s, o);
        if ((t & 63) == 0) sred[t >> 6] = s;
        __syncthreads();
        s = sred[0] + sred[1] + sred[2] + sred[3];
        __syncthreads();
        const float inv = 1.0f / s;
#pragma unroll
        for (int j = 0; j < 4; ++j) {
            v[j].x *= inv; v[j].y *= inv; v[j].z *= inv; v[j].w *= inv;
            Wr[t + j * 256] = v[j];
            cs[j][0] += v[j].x; cs[j][1] += v[j].y;
            cs[j][2] += v[j].z; cs[j][3] += v[j].w;
        }
    }
#pragma unroll
    for (int j = 0; j < 4; ++j)
#pragma unroll
        for (int i = 0; i < 4; ++i)
            atomicAdd(&wsum[4 * t + 1024 * j + i], cs[j][i]);
}

// ---------------------------------------------------------------------------
__global__ __launch_bounds__(256) void usage_kernel(
        const float* __restrict__ usage, const float* __restrict__ wsum,
        float* __restrict__ Uout, float* __restrict__ invw) {
    const int g = blockIdx.x * 256 + threadIdx.x;
    if (g < GP) {
        const float s = wsum[g];
        Uout[g] = usage[g] * DECAY + (s > 0.f ? OMD * s : 0.f);
        invw[g] = 1.0f / (s + EPS);
    }
}

// Final: blended = l2norm(DECAY*pat + OMD*Upart*invw[g]); fallback if !valid.
__global__ __launch_bounds__(256) void finalize_patterns_kernel(
        const float* __restrict__ patterns, const float* __restrict__ wsum,
        const float* __restrict__ invw, const float* __restrict__ Upart,
        float* __restrict__ Pout) {
    __shared__ float sred[4];
    const int g = blockIdx.x;
    const int t = threadIdx.x;
    const float iw = invw[g] * OMD;
    const float4 u4 = ((const float4*)(Upart + (size_t)g * DK))[t];
    const float4 p4 = ((const float4*)(patterns + (size_t)g * DK))[t];
    float4 b;
    b.x = DECAY * p4.x + iw * u4.x;
    b.y = DECAY * p4.y + iw * u4.y;
    b.z = DECAY * p4.z + iw * u4.z;
    b.w = DECAY * p4.w + iw * u4.w;
    float ss = b.x * b.x + b.y * b.y + b.z * b.z + b.w * b.w;
#pragma unroll
    for (int o = 32; o > 0; o >>= 1) ss += __shfl_xor(ss, o);
    if ((t & 63) == 0) sred[t >> 6] = ss;
    __syncthreads();
    const float tot = sred[0] + sred[1] + sred[2] + sred[3];
    const float rs = 1.0f / fmaxf(sqrtf(tot), NORM_EPS);
    float4 o4;
    if (wsum[g] > 0.f) {
        o4.x = b.x * rs; o4.y = b.y * rs; o4.z = b.z * rs; o4.w = b.w * rs;
    } else {
        o4 = p4;
    }
    ((float4*)(Pout + (size_t)g * DK))[t] = o4;
}

// ---------------------------------------------------------------------------
extern "C" void kernel_launch(void* const* d_in, const int* in_sizes, int n_in,
                              void* d_out, int out_size, void* d_ws, size_t ws_size,
                              hipStream_t stream) {
    const float* pair_embed = (const float*)d_in[0];
    const float* patterns   = (const float*)d_in[1];
    const float* usage      = (const float*)d_in[2];

    float* out_w = (float*)d_out;                       // [16384,4096]
    float* out_p = out_w + (size_t)NROWS * GP;          // [4096,1024]
    float* out_u = out_p + (size_t)GP * DK;             // [4096]

    char* ws = (char*)d_ws;
    u16* q_bf   = (u16*)(ws);                            // 32 MiB [16384,1024]; dead after gemm1
    float* Upart = (float*)(ws);                         // 16 MiB [4096,1024] (aliases q_bf)
    u16* pat_bf = (u16*)(ws + 33554432);                 //  8 MiB [4096,1024]
    u16* fT     = (u16*)(ws + 41943040);                 // 32 MiB [1024,16384]
    u16* wT     = (u16*)(ws + 75497472);                 //128 MiB [4096,16384]
    float* hs   = (float*)(ws + 209715200);              // 16 KiB
    float* wsum = (float*)(ws + 209715200 + 16384);      // 16 KiB
    float* invw = (float*)(ws + 209715200 + 32768);      // 16 KiB

    prep_scalars_kernel<<<16, 256, 0, stream>>>(usage, hs, wsum);
    norm_rows_kernel<<<NROWS, 256, 0, stream>>>(pair_embed, q_bf);
    norm_rows_kernel<<<GP, 256, 0, stream>>>(patterns, pat_bf);
    {   // flat^T -> bf16 [1024,16384]
        dim3 g(NROWS / 64, DK / 256);
        transpose_f32_bf16_kernel<<<g, 256, 0, stream>>>(pair_embed, fT, NROWS, DK);
    }
    gemm1_kernel<<<(NROWS / 128) * (GP / 128), 256, 0, stream>>>(q_bf, pat_bf, hs, out_w);
    softmax_kernel<<<NROWS / 32, 256, 0, stream>>>(out_w, wsum);
    usage_kernel<<<16, 256, 0, stream>>>(usage, wsum, out_u, invw);
    // q_bf dead from here on; reuse its space as Upart (stream-ordered).
    zero_kernel<<<(GP * DK / 4) / 256, 256, 0, stream>>>((float4*)Upart);
    {   // weights^T -> bf16 [4096,16384]
        dim3 g(NROWS / 64, GP / 256);
        transpose_f32_bf16_kernel<<<g, 256, 0, stream>>>(out_w, wT, NROWS, GP);
    }
    gemm2_kernel<<<8 * (GP / 128) * (DK / 128), 256, 0, stream>>>(wT, fT, Upart);
    finalize_patterns_kernel<<<GP, 256, 0, stream>>>(patterns, wsum, invw, Upart, out_p);
}